// Round 1
// baseline (385.595 us; speedup 1.0000x reference)
//
#include <hip/hip_runtime.h>

typedef _Float16 f16;
typedef __attribute__((ext_vector_type(8))) _Float16 f16x8;
typedef __attribute__((ext_vector_type(4))) _Float16 f16x4;
typedef __attribute__((ext_vector_type(4))) float f32x4;

#define MFMA(a,b,c) __builtin_amdgcn_mfma_f32_16x16x32_f16(a,b,c,0,0,0)

constexpr int HN = 7, HD = 64, HID = 896, PR = 448;
constexpr int NB = 4, NS = 2048, NM = NB * NS;     // 8192 rows
constexpr float LOG2E = 1.44269504088896f;

// ---------------- kernel 1: fp32 -> f16 conversion into workspace ----------------
__global__ __launch_bounds__(256) void conv_kernel(
    const float* __restrict__ x,  const float* __restrict__ qw,
    const float* __restrict__ kw, const float* __restrict__ vw,
    const float* __restrict__ ow,
    f16* __restrict__ xb, f16* __restrict__ wq, f16* __restrict__ wk,
    f16* __restrict__ wv, f16* __restrict__ wo)
{
    const int XV = NM * HID / 4;   // 1,835,008 float4's of x
    const int WV = PR * HID / 4;   // 100,352 float4's per weight
    const int TOT = XV + 4 * WV;
    int64_t stride = (int64_t)gridDim.x * blockDim.x;
    for (int64_t v = (int64_t)blockIdx.x * 256 + threadIdx.x; v < TOT; v += stride) {
        const float* src; f16* dst; int64_t off;
        if (v < XV)               { src = x;  dst = xb; off = v; }
        else if (v < XV + WV)     { src = qw; dst = wq; off = v - XV; }
        else if (v < XV + 2*WV)   { src = kw; dst = wk; off = v - XV - WV; }
        else if (v < XV + 3*WV)   { src = vw; dst = wv; off = v - XV - 2*WV; }
        else                      { src = ow; dst = wo; off = v - XV - 3*WV; }
        f32x4 fv = *((const f32x4*)src + off);
        f16x4 hv = { (f16)fv[0], (f16)fv[1], (f16)fv[2], (f16)fv[3] };
        *((f16x4*)dst + off) = hv;
    }
}

// ---------------- kernel 2: QKV GEMM + bias + RoPE + layout stores ----------------
// C[8192,448] = xb[8192,896] * w[448,896]^T  for each of q,k,v
// grid: (21, 64)  x = ty*7+nt  (ty in 0..2, nt = head), y = m-tile (128 rows)
__global__ __launch_bounds__(256) void qkv_gemm(
    const f16* __restrict__ xb, const f16* __restrict__ wq,
    const f16* __restrict__ wk, const f16* __restrict__ wv,
    const float* __restrict__ qb, const float* __restrict__ kb,
    const float* __restrict__ vb,
    const float* __restrict__ cosT, const float* __restrict__ sinT,
    f16* __restrict__ Q, f16* __restrict__ K, f16* __restrict__ Vt)
{
    extern __shared__ char smem[];
    f16*  As = (f16*)smem;                  // [128][64] f16, chunk-swizzled
    f16*  Bs = (f16*)(smem + 128*64*2);     // [64][64]
    float* Cs = (float*)smem;               // [128][65] fp32 (epilogue reuse)

    const int ty = blockIdx.x / 7;          // 0=q 1=k 2=v
    const int nt = blockIdx.x % 7;          // head
    const int mt = blockIdx.y;
    const int m0 = mt * 128, n0 = nt * 64;

    const f16* w = (ty == 0) ? wq : (ty == 1) ? wk : wv;
    const float* bias = (ty == 0) ? qb : (ty == 1) ? kb : vb;

    const int tid = threadIdx.x;
    const int wid = tid >> 6, lane = tid & 63;
    const int wm = wid >> 1, wn = wid & 1;   // 2x2 wave grid: 64x32 per wave
    const int lg = lane >> 4, lr = lane & 15;

    f32x4 acc[4][2] = {};

    for (int k0 = 0; k0 < HID; k0 += 64) {
        // stage A (128x64), 4 passes; XOR-swizzle chunk index by row&7
        #pragma unroll
        for (int p = 0; p < 4; p++) {
            int r = p*32 + (tid >> 3), c = tid & 7;
            f16x8 v = *(const f16x8*)(xb + (int64_t)(m0 + r)*HID + k0 + c*8);
            *(f16x8*)(As + r*64 + ((c ^ (r & 7)) * 8)) = v;
        }
        // stage B (64x64), 2 passes
        #pragma unroll
        for (int p = 0; p < 2; p++) {
            int r = p*32 + (tid >> 3), c = tid & 7;
            f16x8 v = *(const f16x8*)(w + (int64_t)(n0 + r)*HID + k0 + c*8);
            *(f16x8*)(Bs + r*64 + ((c ^ (r & 7)) * 8)) = v;
        }
        __syncthreads();
        #pragma unroll
        for (int kc = 0; kc < 2; kc++) {
            f16x8 af[4], bf[2];
            #pragma unroll
            for (int fm = 0; fm < 4; fm++) {
                int r = wm*64 + fm*16 + lr;
                int c = kc*4 + lg;
                af[fm] = *(const f16x8*)(As + r*64 + ((c ^ (r & 7)) * 8));
            }
            #pragma unroll
            for (int fn = 0; fn < 2; fn++) {
                int r = wn*32 + fn*16 + lr;
                int c = kc*4 + lg;
                bf[fn] = *(const f16x8*)(Bs + r*64 + ((c ^ (r & 7)) * 8));
            }
            #pragma unroll
            for (int fm = 0; fm < 4; fm++)
                #pragma unroll
                for (int fn = 0; fn < 2; fn++)
                    acc[fm][fn] = MFMA(af[fm], bf[fn], acc[fm][fn]);
        }
        __syncthreads();
    }

    // epilogue: acc -> Cs (fp32, +bias)
    #pragma unroll
    for (int fm = 0; fm < 4; fm++)
        #pragma unroll
        for (int fn = 0; fn < 2; fn++)
            #pragma unroll
            for (int j = 0; j < 4; j++) {
                int r = wm*64 + fm*16 + lg*4 + j;
                int c = wn*32 + fn*16 + lr;
                Cs[r*65 + c] = acc[fm][fn][j] + bias[n0 + c];
            }
    __syncthreads();

    const int b = m0 / NS;
    const int s0 = m0 % NS;
    if (ty < 2) {
        // RoPE + store [b][h][s][64]; Q pre-scaled by 1/sqrt(64)
        f16* dst = (ty == 0) ? Q : K;
        const float scale = (ty == 0) ? 0.125f : 1.0f;
        int r = tid >> 1, d0 = (tid & 1) * 32;
        int s = s0 + r;
        f16 vals[32];
        #pragma unroll
        for (int i = 0; i < 32; i++) {
            int d = d0 + i;
            float y  = Cs[r*65 + d];
            float yo = Cs[r*65 + (d ^ 32)];
            float rot = (d < 32) ? -yo : yo;
            float val = (y * cosT[s*64 + d] + rot * sinT[s*64 + d]) * scale;
            vals[i] = (f16)val;
        }
        f16* p = dst + (((int64_t)(b*HN + nt)) * NS + s) * HD + d0;
        #pragma unroll
        for (int i = 0; i < 4; i++)
            *(f16x8*)(p + i*8) = *(f16x8*)(vals + i*8);
    } else {
        // V transposed store: Vt[b][h][d][s]
        int d = tid >> 2, si = (tid & 3) * 32;
        f16 vals[32];
        #pragma unroll
        for (int i = 0; i < 32; i++)
            vals[i] = (f16)Cs[(si + i)*65 + d];
        f16* p = Vt + (((int64_t)(b*HN + nt)) * HD + d) * NS + s0 + si;
        #pragma unroll
        for (int i = 0; i < 4; i++)
            *(f16x8*)(p + i*8) = *(f16x8*)(vals + i*8);
    }
}

// ---------------- kernel 3: flash attention ----------------
// grid: (32 q-blocks, 28 bh). block = 256 (4 waves x 16 q-rows).
__global__ __launch_bounds__(256) void attn_kernel(
    const f16* __restrict__ Q, const f16* __restrict__ K,
    const f16* __restrict__ Vt, f16* __restrict__ O)
{
    __shared__ __align__(16) f16 Pl[4][16][80];   // per-wave P tile, padded

    const int qb = blockIdx.x, bh = blockIdx.y;
    const int tid = threadIdx.x, wid = tid >> 6, lane = tid & 63;
    const int lg = lane >> 4, lr = lane & 15;
    const int q0 = qb*64 + wid*16;

    const f16* Qp = Q + (int64_t)bh * NS * HD;
    const f16* Kp = K + (int64_t)bh * NS * HD;
    const f16* Vp = Vt + (int64_t)bh * HD * NS;

    f16x8 aq[2];
    aq[0] = *(const f16x8*)(Qp + (q0 + lr)*HD + lg*8);
    aq[1] = *(const f16x8*)(Qp + (q0 + lr)*HD + 32 + lg*8);

    f32x4 accO[4] = {};
    float mrun[4], srun[4];
    #pragma unroll
    for (int j = 0; j < 4; j++) { mrun[j] = -1e30f; srun[j] = 0.f; }

    for (int kv0 = 0; kv0 < NS; kv0 += 64) {
        f32x4 sf[4];
        #pragma unroll
        for (int kt = 0; kt < 4; kt++) {
            const f16* kr = Kp + (int64_t)(kv0 + kt*16 + lr) * HD;
            f16x8 b0 = *(const f16x8*)(kr + lg*8);
            f16x8 b1 = *(const f16x8*)(kr + 32 + lg*8);
            f32x4 z = {};
            z = MFMA(aq[0], b0, z);
            z = MFMA(aq[1], b1, z);
            sf[kt] = z;
        }
        float tmax[4];
        #pragma unroll
        for (int j = 0; j < 4; j++)
            tmax[j] = fmaxf(fmaxf(sf[0][j], sf[1][j]), fmaxf(sf[2][j], sf[3][j]));
        #pragma unroll
        for (int off = 1; off < 16; off <<= 1)
            #pragma unroll
            for (int j = 0; j < 4; j++)
                tmax[j] = fmaxf(tmax[j], __shfl_xor(tmax[j], off, 64));
        float corr[4];
        #pragma unroll
        for (int j = 0; j < 4; j++) {
            float mn = fmaxf(mrun[j], tmax[j]);
            corr[j] = exp2f((mrun[j] - mn) * LOG2E);
            mrun[j] = mn;
        }
        float tsum[4] = {0.f, 0.f, 0.f, 0.f};
        #pragma unroll
        for (int kt = 0; kt < 4; kt++)
            #pragma unroll
            for (int j = 0; j < 4; j++) {
                float p = exp2f((sf[kt][j] - mrun[j]) * LOG2E);
                sf[kt][j] = p; tsum[j] += p;
            }
        #pragma unroll
        for (int off = 1; off < 16; off <<= 1)
            #pragma unroll
            for (int j = 0; j < 4; j++)
                tsum[j] += __shfl_xor(tsum[j], off, 64);
        #pragma unroll
        for (int j = 0; j < 4; j++)
            srun[j] = srun[j]*corr[j] + tsum[j];
        #pragma unroll
        for (int fn = 0; fn < 4; fn++)
            #pragma unroll
            for (int j = 0; j < 4; j++)
                accO[fn][j] *= corr[j];
        // P -> LDS (D-layout -> A-layout transpose through per-wave tile)
        #pragma unroll
        for (int kt = 0; kt < 4; kt++)
            #pragma unroll
            for (int j = 0; j < 4; j++)
                Pl[wid][lg*4 + j][kt*16 + lr] = (f16)sf[kt][j];
        // PV
        #pragma unroll
        for (int kc = 0; kc < 2; kc++) {
            f16x8 ap = *(const f16x8*)(&Pl[wid][lr][kc*32 + lg*8]);
            #pragma unroll
            for (int fn = 0; fn < 4; fn++) {
                f16x8 bv = *(const f16x8*)(Vp + (int64_t)(fn*16 + lr)*NS + kv0 + kc*32 + lg*8);
                accO[fn] = MFMA(ap, bv, accO[fn]);
            }
        }
    }

    const int b = bh / HN, h = bh % HN;
    #pragma unroll
    for (int fn = 0; fn < 4; fn++)
        #pragma unroll
        for (int j = 0; j < 4; j++) {
            int q = q0 + lg*4 + j;
            int d = fn*16 + lr;
            float v = accO[fn][j] / srun[j];
            O[((int64_t)b*NS + q) * PR + h*HD + d] = (f16)v;
        }
}

// ---------------- kernel 4: output projection ----------------
// out[8192,896] = O[8192,448] * wo[896,448]^T + ob   (fp32 out)
// grid: (14, 64)
__global__ __launch_bounds__(256) void oproj_gemm(
    const f16* __restrict__ Ob, const f16* __restrict__ wo,
    const float* __restrict__ ob, float* __restrict__ out)
{
    extern __shared__ char smem[];
    f16* As = (f16*)smem;                 // [128][64]
    f16* Bs = (f16*)(smem + 128*64*2);    // [64][64]

    const int nt = blockIdx.x, mt = blockIdx.y;
    const int m0 = mt*128, n0 = nt*64;
    const int tid = threadIdx.x;
    const int wid = tid >> 6, lane = tid & 63;
    const int wm = wid >> 1, wn = wid & 1;
    const int lg = lane >> 4, lr = lane & 15;

    f32x4 acc[4][2] = {};

    for (int k0 = 0; k0 < PR; k0 += 64) {
        #pragma unroll
        for (int p = 0; p < 4; p++) {
            int r = p*32 + (tid >> 3), c = tid & 7;
            f16x8 v = *(const f16x8*)(Ob + (int64_t)(m0 + r)*PR + k0 + c*8);
            *(f16x8*)(As + r*64 + ((c ^ (r & 7)) * 8)) = v;
        }
        #pragma unroll
        for (int p = 0; p < 2; p++) {
            int r = p*32 + (tid >> 3), c = tid & 7;
            f16x8 v = *(const f16x8*)(wo + (int64_t)(n0 + r)*PR + k0 + c*8);
            *(f16x8*)(Bs + r*64 + ((c ^ (r & 7)) * 8)) = v;
        }
        __syncthreads();
        #pragma unroll
        for (int kc = 0; kc < 2; kc++) {
            f16x8 af[4], bf[2];
            #pragma unroll
            for (int fm = 0; fm < 4; fm++) {
                int r = wm*64 + fm*16 + lr;
                int c = kc*4 + lg;
                af[fm] = *(const f16x8*)(As + r*64 + ((c ^ (r & 7)) * 8));
            }
            #pragma unroll
            for (int fn = 0; fn < 2; fn++) {
                int r = wn*32 + fn*16 + lr;
                int c = kc*4 + lg;
                bf[fn] = *(const f16x8*)(Bs + r*64 + ((c ^ (r & 7)) * 8));
            }
            #pragma unroll
            for (int fm = 0; fm < 4; fm++)
                #pragma unroll
                for (int fn = 0; fn < 2; fn++)
                    acc[fm][fn] = MFMA(af[fm], bf[fn], acc[fm][fn]);
        }
        __syncthreads();
    }

    #pragma unroll
    for (int fm = 0; fm < 4; fm++)
        #pragma unroll
        for (int fn = 0; fn < 2; fn++)
            #pragma unroll
            for (int j = 0; j < 4; j++) {
                int row = m0 + wm*64 + fm*16 + lg*4 + j;
                int col = n0 + wn*32 + fn*16 + lr;
                out[(int64_t)row*HID + col] = acc[fm][fn][j] + ob[col];
            }
}

extern "C" void kernel_launch(void* const* d_in, const int* in_sizes, int n_in,
                              void* d_out, int out_size, void* d_ws, size_t ws_size,
                              hipStream_t stream) {
    const float* x    = (const float*)d_in[0];
    const float* cosT = (const float*)d_in[1];
    const float* sinT = (const float*)d_in[2];
    const float* qw   = (const float*)d_in[3];
    const float* qb   = (const float*)d_in[4];
    const float* kw   = (const float*)d_in[5];
    const float* kb   = (const float*)d_in[6];
    const float* vw   = (const float*)d_in[7];
    const float* vb   = (const float*)d_in[8];
    const float* ow   = (const float*)d_in[9];
    const float* ob   = (const float*)d_in[10];
    float* out = (float*)d_out;

    char* ws = (char*)d_ws;
    f16* xb = (f16*)ws;  ws += (size_t)NM * HID * 2;          // 14.68 MB
    f16* wqf = (f16*)ws; ws += (size_t)PR * HID * 2;
    f16* wkf = (f16*)ws; ws += (size_t)PR * HID * 2;
    f16* wvf = (f16*)ws; ws += (size_t)PR * HID * 2;
    f16* wof = (f16*)ws; ws += (size_t)HID * PR * 2;
    f16* Qb = (f16*)ws;  ws += (size_t)NB * HN * NS * HD * 2; // 7.34 MB
    f16* Kb = (f16*)ws;  ws += (size_t)NB * HN * NS * HD * 2;
    f16* Vt = (f16*)ws;  ws += (size_t)NB * HN * HD * NS * 2;
    f16* Obuf = (f16*)ws; ws += (size_t)NM * PR * 2;

    conv_kernel<<<dim3(2048), dim3(256), 0, stream>>>(x, qw, kw, vw, ow, xb, wqf, wkf, wvf, wof);
    qkv_gemm<<<dim3(21, 64), dim3(256), 33280, stream>>>(xb, wqf, wkf, wvf, qb, kb, vb, cosT, sinT, Qb, Kb, Vt);
    attn_kernel<<<dim3(32, 28), dim3(256), 0, stream>>>(Qb, Kb, Vt, Obuf);
    oproj_gemm<<<dim3(14, 64), dim3(256), 24576, stream>>>(Obuf, wof, ob, out);
}

// Round 2
// 256.572 us; speedup vs baseline: 1.5029x; 1.5029x over previous
//
#include <hip/hip_runtime.h>

typedef _Float16 f16;
typedef __attribute__((ext_vector_type(8))) _Float16 f16x8;
typedef __attribute__((ext_vector_type(4))) _Float16 f16x4;
typedef __attribute__((ext_vector_type(4))) float f32x4;

#define MFMA(a,b,c) __builtin_amdgcn_mfma_f32_16x16x32_f16(a,b,c,0,0,0)

constexpr int HN = 7, HD = 64, HID = 896, PR = 448;
constexpr int NB = 4, NS = 2048, NM = NB * NS;     // 8192 rows
constexpr float LOG2E = 1.44269504088896f;

__device__ __forceinline__ void gload16(const f16* g, f16* l) {
    __builtin_amdgcn_global_load_lds(
        (const __attribute__((address_space(1))) void*)g,
        (__attribute__((address_space(3))) void*)l,
        16, 0, 0);
}

// ---------------- kernel 1: fp32 -> f16 conversion into workspace ----------------
__global__ __launch_bounds__(256) void conv_kernel(
    const float* __restrict__ x,  const float* __restrict__ qw,
    const float* __restrict__ kw, const float* __restrict__ vw,
    const float* __restrict__ ow,
    f16* __restrict__ xb, f16* __restrict__ wq, f16* __restrict__ wk,
    f16* __restrict__ wv, f16* __restrict__ wo)
{
    const int XV = NM * HID / 4;
    const int WV = PR * HID / 4;
    const int TOT = XV + 4 * WV;
    int64_t stride = (int64_t)gridDim.x * blockDim.x;
    for (int64_t v = (int64_t)blockIdx.x * 256 + threadIdx.x; v < TOT; v += stride) {
        const float* src; f16* dst; int64_t off;
        if (v < XV)               { src = x;  dst = xb; off = v; }
        else if (v < XV + WV)     { src = qw; dst = wq; off = v - XV; }
        else if (v < XV + 2*WV)   { src = kw; dst = wk; off = v - XV - WV; }
        else if (v < XV + 3*WV)   { src = vw; dst = wv; off = v - XV - 2*WV; }
        else                      { src = ow; dst = wo; off = v - XV - 3*WV; }
        f32x4 fv = *((const f32x4*)src + off);
        f16x4 hv = { (f16)fv[0], (f16)fv[1], (f16)fv[2], (f16)fv[3] };
        *((f16x4*)dst + off) = hv;
    }
}

// ---------------- kernel 2: QKV GEMM + bias + RoPE + layout stores ----------------
// Q stored [bh][s][64] (pre-scaled by 0.125*log2e).
// K stored tiled+swizzled: [bh][s/64][s%64][ (d/8 ^ (s&7))*8 + d%8 ]
// V stored transposed tiled+swizzled: [bh][s/64][d][ ((s%64)/8 ^ (d&7))*8 + s%8 ]
__global__ __launch_bounds__(256) void qkv_gemm(
    const f16* __restrict__ xb, const f16* __restrict__ wq,
    const f16* __restrict__ wk, const f16* __restrict__ wv,
    const float* __restrict__ qb, const float* __restrict__ kb,
    const float* __restrict__ vb,
    const float* __restrict__ cosT, const float* __restrict__ sinT,
    f16* __restrict__ Q, f16* __restrict__ K, f16* __restrict__ Vt)
{
    extern __shared__ char smem[];
    f16*  As = (f16*)smem;                  // [128][64] f16, chunk-swizzled
    f16*  Bs = (f16*)(smem + 128*64*2);     // [64][64]
    float* Cs = (float*)smem;               // [128][65] fp32 (epilogue reuse)

    const int ty = blockIdx.x / 7;          // 0=q 1=k 2=v
    const int nt = blockIdx.x % 7;          // head
    const int mt = blockIdx.y;
    const int m0 = mt * 128, n0 = nt * 64;

    const f16* w = (ty == 0) ? wq : (ty == 1) ? wk : wv;
    const float* bias = (ty == 0) ? qb : (ty == 1) ? kb : vb;

    const int tid = threadIdx.x;
    const int wid = tid >> 6, lane = tid & 63;
    const int wm = wid >> 1, wn = wid & 1;
    const int lg = lane >> 4, lr = lane & 15;

    f32x4 acc[4][2] = {};

    for (int k0 = 0; k0 < HID; k0 += 64) {
        #pragma unroll
        for (int p = 0; p < 4; p++) {
            int r = p*32 + (tid >> 3), c = tid & 7;
            f16x8 v = *(const f16x8*)(xb + (int64_t)(m0 + r)*HID + k0 + c*8);
            *(f16x8*)(As + r*64 + ((c ^ (r & 7)) * 8)) = v;
        }
        #pragma unroll
        for (int p = 0; p < 2; p++) {
            int r = p*32 + (tid >> 3), c = tid & 7;
            f16x8 v = *(const f16x8*)(w + (int64_t)(n0 + r)*HID + k0 + c*8);
            *(f16x8*)(Bs + r*64 + ((c ^ (r & 7)) * 8)) = v;
        }
        __syncthreads();
        #pragma unroll
        for (int kc = 0; kc < 2; kc++) {
            f16x8 af[4], bf[2];
            #pragma unroll
            for (int fm = 0; fm < 4; fm++) {
                int r = wm*64 + fm*16 + lr;
                int c = kc*4 + lg;
                af[fm] = *(const f16x8*)(As + r*64 + ((c ^ (r & 7)) * 8));
            }
            #pragma unroll
            for (int fn = 0; fn < 2; fn++) {
                int r = wn*32 + fn*16 + lr;
                int c = kc*4 + lg;
                bf[fn] = *(const f16x8*)(Bs + r*64 + ((c ^ (r & 7)) * 8));
            }
            #pragma unroll
            for (int fm = 0; fm < 4; fm++)
                #pragma unroll
                for (int fn = 0; fn < 2; fn++)
                    acc[fm][fn] = MFMA(af[fm], bf[fn], acc[fm][fn]);
        }
        __syncthreads();
    }

    #pragma unroll
    for (int fm = 0; fm < 4; fm++)
        #pragma unroll
        for (int fn = 0; fn < 2; fn++)
            #pragma unroll
            for (int j = 0; j < 4; j++) {
                int r = wm*64 + fm*16 + lg*4 + j;
                int c = wn*32 + fn*16 + lr;
                Cs[r*65 + c] = acc[fm][fn][j] + bias[n0 + c];
            }
    __syncthreads();

    const int b = m0 / NS;
    const int s0 = m0 % NS;
    const int64_t bhbase = ((int64_t)(b*HN + nt)) * NS * HD;
    if (ty < 2) {
        // RoPE; Q pre-scaled by 1/sqrt(64)*log2e
        const float scale = (ty == 0) ? 0.125f * LOG2E : 1.0f;
        int r = tid >> 1, d0 = (tid & 1) * 32;
        int s = s0 + r;
        f16 vals[32];
        #pragma unroll
        for (int i = 0; i < 32; i++) {
            int d = d0 + i;
            float y  = Cs[r*65 + d];
            float yo = Cs[r*65 + (d ^ 32)];
            float rot = (d < 32) ? -yo : yo;
            float val = (y * cosT[s*64 + d] + rot * sinT[s*64 + d]) * scale;
            vals[i] = (f16)val;
        }
        if (ty == 0) {
            f16* p = Q + bhbase + (int64_t)s * HD + d0;
            #pragma unroll
            for (int i = 0; i < 4; i++)
                *(f16x8*)(p + i*8) = *(f16x8*)(vals + i*8);
        } else {
            int tt = (s0 >> 6) + (r >> 6);
            int rt = r & 63;
            f16* base = K + bhbase + tt*4096 + rt*64;
            #pragma unroll
            for (int i = 0; i < 4; i++) {
                int pos = ((d0 >> 3) + i) ^ (rt & 7);
                *(f16x8*)(base + pos*8) = *(f16x8*)(vals + i*8);
            }
        }
    } else {
        int d = tid >> 2, si = (tid & 3) * 32;
        f16 vals[32];
        #pragma unroll
        for (int i = 0; i < 32; i++)
            vals[i] = (f16)Cs[(si + i)*65 + d];
        int tt = (s0 >> 6) + (si >> 6);
        int sb = si & 63;
        f16* base = Vt + bhbase + tt*4096 + d*64;
        #pragma unroll
        for (int i = 0; i < 4; i++) {
            int pos = ((sb >> 3) + i) ^ (d & 7);
            *(f16x8*)(base + pos*8) = *(f16x8*)(vals + i*8);
        }
    }
}

// ---------------- kernel 3: flash attention (swapped-operand, LDS-staged KV) ----------------
// grid: (32 q-blocks, 28 bh). block = 256 (4 waves x 16 q-rows).
__global__ __launch_bounds__(256) void attn_kernel(
    const f16* __restrict__ Q, const f16* __restrict__ K2,
    const f16* __restrict__ V2, f16* __restrict__ O)
{
    __shared__ __align__(16) f16 KVs[2][2][4096];   // [buf][K/V][64x64 swizzled]
    __shared__ __align__(16) f16 Pl[4][16][72];     // per-wave P: [q][k], pad 72

    const int qb = blockIdx.x, bh = blockIdx.y;
    const int tid = threadIdx.x, w = tid >> 6, lane = tid & 63;
    const int g = lane >> 4, lr = lane & 15;
    const int q0 = qb * 64 + w * 16;

    const int64_t bhoff = (int64_t)bh * NS * HD;
    const f16* Qp = Q + bhoff;
    const f16* Kp = K2 + bhoff;
    const f16* Vp = V2 + bhoff;

    // Q B-fragments: col=q0+lr, k-chunk c -> d = c*32 + g*8 + 0..7
    f16x8 aq0 = *(const f16x8*)(Qp + (q0 + lr) * HD + g * 8);
    f16x8 aq1 = *(const f16x8*)(Qp + (q0 + lr) * HD + 32 + g * 8);

    const int stoff = w * 1024 + lane * 8;   // per-lane f16 src offset in tile
    const int ldoff = w * 1024;              // wave-uniform LDS f16 base

    // stage tile 0 into buf 0
    gload16(Kp + stoff,       &KVs[0][0][ldoff]);
    gload16(Kp + stoff + 512, &KVs[0][0][ldoff + 512]);
    gload16(Vp + stoff,       &KVs[0][1][ldoff]);
    gload16(Vp + stoff + 512, &KVs[0][1][ldoff + 512]);
    __syncthreads();

    f32x4 accO[4] = {};
    float mrun = -1e30f, srun = 0.f;

    const int ch0 = (g ^ (lr & 7)) * 8;         // swizzled f16 offset, k-chunk 0
    const int ch1 = ((4 + g) ^ (lr & 7)) * 8;   // k-chunk 1

    int buf = 0;
    for (int t = 0; t < NS / 64; ++t) {
        if (t + 1 < NS / 64) {
            const f16* ks = Kp + (t + 1) * 4096 + stoff;
            const f16* vs = Vp + (t + 1) * 4096 + stoff;
            gload16(ks,       &KVs[buf ^ 1][0][ldoff]);
            gload16(ks + 512, &KVs[buf ^ 1][0][ldoff + 512]);
            gload16(vs,       &KVs[buf ^ 1][1][ldoff]);
            gload16(vs + 512, &KVs[buf ^ 1][1][ldoff + 512]);
        }
        const f16* Ks = &KVs[buf][0][0];
        const f16* Vs = &KVs[buf][1][0];

        // QK^T swapped: D[k][q], k = kt*16 + g*4 + j, q = lr
        f32x4 sf[4];
        #pragma unroll
        for (int kt = 0; kt < 4; ++kt) {
            const f16* kl = Ks + (kt * 16 + lr) * 64;
            f16x8 k0 = *(const f16x8*)(kl + ch0);
            f16x8 k1 = *(const f16x8*)(kl + ch1);
            f32x4 z = {};
            z = MFMA(k0, aq0, z);
            z = MFMA(k1, aq1, z);
            sf[kt] = z;
        }

        // row max: in-register tree + 2 shfls
        float m00 = fmaxf(fmaxf(sf[0][0], sf[0][1]), fmaxf(sf[0][2], sf[0][3]));
        float m01 = fmaxf(fmaxf(sf[1][0], sf[1][1]), fmaxf(sf[1][2], sf[1][3]));
        float m10 = fmaxf(fmaxf(sf[2][0], sf[2][1]), fmaxf(sf[2][2], sf[2][3]));
        float m11 = fmaxf(fmaxf(sf[3][0], sf[3][1]), fmaxf(sf[3][2], sf[3][3]));
        float pmax = fmaxf(fmaxf(m00, m01), fmaxf(m10, m11));
        pmax = fmaxf(pmax, __shfl_xor(pmax, 16, 64));
        pmax = fmaxf(pmax, __shfl_xor(pmax, 32, 64));

        float mn = fmaxf(mrun, pmax);
        float corr = exp2f(mrun - mn);
        mrun = mn;

        float pf[16];
        #pragma unroll
        for (int kt = 0; kt < 4; ++kt)
            #pragma unroll
            for (int j = 0; j < 4; ++j)
                pf[kt*4 + j] = exp2f(sf[kt][j] - mn);

        // tree sum + 2 shfls
        float s0a = (pf[0] + pf[1]) + (pf[2] + pf[3]);
        float s1a = (pf[4] + pf[5]) + (pf[6] + pf[7]);
        float s2a = (pf[8] + pf[9]) + (pf[10] + pf[11]);
        float s3a = (pf[12] + pf[13]) + (pf[14] + pf[15]);
        float tsum = (s0a + s1a) + (s2a + s3a);
        tsum += __shfl_xor(tsum, 16, 64);
        tsum += __shfl_xor(tsum, 32, 64);
        srun = srun * corr + tsum;

        #pragma unroll
        for (int fn = 0; fn < 4; ++fn)
            #pragma unroll
            for (int j = 0; j < 4; ++j)
                accO[fn][j] *= corr;

        // P -> per-wave LDS tile Pl[q][k] (4 x b64 writes)
        #pragma unroll
        for (int kt = 0; kt < 4; ++kt) {
            f16x4 pk = { (f16)pf[kt*4+0], (f16)pf[kt*4+1], (f16)pf[kt*4+2], (f16)pf[kt*4+3] };
            *(f16x4*)&Pl[w][lr][kt*16 + g*4] = pk;
        }
        // P B-fragments: col=q=lr, k = c*32 + g*8 + 0..7
        f16x8 p0 = *(const f16x8*)&Pl[w][lr][g * 8];
        f16x8 p1 = *(const f16x8*)&Pl[w][lr][32 + g * 8];

        // PV swapped: D[d][q], A = V^T rows d, B = P
        #pragma unroll
        for (int fn = 0; fn < 4; ++fn) {
            const f16* vl = Vs + (fn * 16 + lr) * 64;
            f16x8 v0 = *(const f16x8*)(vl + ch0);
            f16x8 v1 = *(const f16x8*)(vl + ch1);
            accO[fn] = MFMA(v0, p0, accO[fn]);
            accO[fn] = MFMA(v1, p1, accO[fn]);
        }
        __syncthreads();
        buf ^= 1;
    }

    const int b = bh / HN, h = bh % HN;
    const float inv = 1.0f / srun;
    const int q = q0 + lr;
    f16* orow = O + ((int64_t)b * NS + q) * PR + h * HD;
    #pragma unroll
    for (int fn = 0; fn < 4; ++fn) {
        f16x4 hv = { (f16)(accO[fn][0] * inv), (f16)(accO[fn][1] * inv),
                     (f16)(accO[fn][2] * inv), (f16)(accO[fn][3] * inv) };
        *(f16x4*)(orow + fn * 16 + g * 4) = hv;
    }
}

// ---------------- kernel 4: output projection ----------------
__global__ __launch_bounds__(256) void oproj_gemm(
    const f16* __restrict__ Ob, const f16* __restrict__ wo,
    const float* __restrict__ ob, float* __restrict__ out)
{
    extern __shared__ char smem[];
    f16* As = (f16*)smem;                 // [128][64]
    f16* Bs = (f16*)(smem + 128*64*2);    // [64][64]

    const int nt = blockIdx.x, mt = blockIdx.y;
    const int m0 = mt*128, n0 = nt*64;
    const int tid = threadIdx.x;
    const int wid = tid >> 6, lane = tid & 63;
    const int wm = wid >> 1, wn = wid & 1;
    const int lg = lane >> 4, lr = lane & 15;

    f32x4 acc[4][2] = {};

    for (int k0 = 0; k0 < PR; k0 += 64) {
        #pragma unroll
        for (int p = 0; p < 4; p++) {
            int r = p*32 + (tid >> 3), c = tid & 7;
            f16x8 v = *(const f16x8*)(Ob + (int64_t)(m0 + r)*PR + k0 + c*8);
            *(f16x8*)(As + r*64 + ((c ^ (r & 7)) * 8)) = v;
        }
        #pragma unroll
        for (int p = 0; p < 2; p++) {
            int r = p*32 + (tid >> 3), c = tid & 7;
            f16x8 v = *(const f16x8*)(wo + (int64_t)(n0 + r)*PR + k0 + c*8);
            *(f16x8*)(Bs + r*64 + ((c ^ (r & 7)) * 8)) = v;
        }
        __syncthreads();
        #pragma unroll
        for (int kc = 0; kc < 2; kc++) {
            f16x8 af[4], bf[2];
            #pragma unroll
            for (int fm = 0; fm < 4; fm++) {
                int r = wm*64 + fm*16 + lr;
                int c = kc*4 + lg;
                af[fm] = *(const f16x8*)(As + r*64 + ((c ^ (r & 7)) * 8));
            }
            #pragma unroll
            for (int fn = 0; fn < 2; fn++) {
                int r = wn*32 + fn*16 + lr;
                int c = kc*4 + lg;
                bf[fn] = *(const f16x8*)(Bs + r*64 + ((c ^ (r & 7)) * 8));
            }
            #pragma unroll
            for (int fm = 0; fm < 4; fm++)
                #pragma unroll
                for (int fn = 0; fn < 2; fn++)
                    acc[fm][fn] = MFMA(af[fm], bf[fn], acc[fm][fn]);
        }
        __syncthreads();
    }

    #pragma unroll
    for (int fm = 0; fm < 4; fm++)
        #pragma unroll
        for (int fn = 0; fn < 2; fn++)
            #pragma unroll
            for (int j = 0; j < 4; j++) {
                int row = m0 + wm*64 + fm*16 + lg*4 + j;
                int col = n0 + wn*32 + fn*16 + lr;
                out[(int64_t)row*HID + col] = acc[fm][fn][j] + ob[col];
            }
}

extern "C" void kernel_launch(void* const* d_in, const int* in_sizes, int n_in,
                              void* d_out, int out_size, void* d_ws, size_t ws_size,
                              hipStream_t stream) {
    const float* x    = (const float*)d_in[0];
    const float* cosT = (const float*)d_in[1];
    const float* sinT = (const float*)d_in[2];
    const float* qw   = (const float*)d_in[3];
    const float* qb   = (const float*)d_in[4];
    const float* kw   = (const float*)d_in[5];
    const float* kb   = (const float*)d_in[6];
    const float* vw   = (const float*)d_in[7];
    const float* vb   = (const float*)d_in[8];
    const float* ow   = (const float*)d_in[9];
    const float* ob   = (const float*)d_in[10];
    float* out = (float*)d_out;

    char* ws = (char*)d_ws;
    f16* xb = (f16*)ws;  ws += (size_t)NM * HID * 2;
    f16* wqf = (f16*)ws; ws += (size_t)PR * HID * 2;
    f16* wkf = (f16*)ws; ws += (size_t)PR * HID * 2;
    f16* wvf = (f16*)ws; ws += (size_t)PR * HID * 2;
    f16* wof = (f16*)ws; ws += (size_t)HID * PR * 2;
    f16* Qb = (f16*)ws;  ws += (size_t)NB * HN * NS * HD * 2;
    f16* Kb = (f16*)ws;  ws += (size_t)NB * HN * NS * HD * 2;
    f16* Vt = (f16*)ws;  ws += (size_t)NB * HN * HD * NS * 2;
    f16* Obuf = (f16*)ws; ws += (size_t)NM * PR * 2;

    conv_kernel<<<dim3(2048), dim3(256), 0, stream>>>(x, qw, kw, vw, ow, xb, wqf, wkf, wvf, wof);
    qkv_gemm<<<dim3(21, 64), dim3(256), 33280, stream>>>(xb, wqf, wkf, wvf, qb, kb, vb, cosT, sinT, Qb, Kb, Vt);
    attn_kernel<<<dim3(32, 28), dim3(256), 0, stream>>>(Qb, Kb, Vt, Obuf);
    oproj_gemm<<<dim3(14, 64), dim3(256), 24576, stream>>>(Obuf, wof, ob, out);
}

// Round 3
// 254.456 us; speedup vs baseline: 1.5154x; 1.0083x over previous
//
#include <hip/hip_runtime.h>

typedef _Float16 f16;
typedef __attribute__((ext_vector_type(8))) _Float16 f16x8;
typedef __attribute__((ext_vector_type(4))) _Float16 f16x4;
typedef __attribute__((ext_vector_type(4))) float f32x4;

#define MFMA(a,b,c) __builtin_amdgcn_mfma_f32_16x16x32_f16(a,b,c,0,0,0)

constexpr int HN = 7, HD = 64, HID = 896, PR = 448;
constexpr int NB = 4, NS = 2048, NM = NB * NS;
constexpr float LOG2E = 1.44269504088896f;

__device__ __forceinline__ void gload16(const f16* g, f16* l) {
    __builtin_amdgcn_global_load_lds(
        (const __attribute__((address_space(1))) void*)g,
        (__attribute__((address_space(3))) void*)l,
        16, 0, 0);
}

__device__ __forceinline__ int xcd_swz(int orig, int per) {
    return (orig & 7) * per + (orig >> 3);
}

// ---------------- kernel 1: fp32 -> f16 conversion ----------------
__global__ __launch_bounds__(256) void conv_kernel(
    const float* __restrict__ x,  const float* __restrict__ qw,
    const float* __restrict__ kw, const float* __restrict__ vw,
    const float* __restrict__ ow,
    f16* __restrict__ xb, f16* __restrict__ wq, f16* __restrict__ wk,
    f16* __restrict__ wv, f16* __restrict__ wo)
{
    const int XV = NM * HID / 4;
    const int WV = PR * HID / 4;
    const int TOT = XV + 4 * WV;
    int64_t stride = (int64_t)gridDim.x * blockDim.x;
    for (int64_t v = (int64_t)blockIdx.x * 256 + threadIdx.x; v < TOT; v += stride) {
        const float* src; f16* dst; int64_t off;
        if (v < XV)               { src = x;  dst = xb; off = v; }
        else if (v < XV + WV)     { src = qw; dst = wq; off = v - XV; }
        else if (v < XV + 2*WV)   { src = kw; dst = wk; off = v - XV - WV; }
        else if (v < XV + 3*WV)   { src = vw; dst = wv; off = v - XV - 2*WV; }
        else                      { src = ow; dst = wo; off = v - XV - 3*WV; }
        f32x4 fv = *((const f32x4*)src + off);
        f16x4 hv = { (f16)fv[0], (f16)fv[1], (f16)fv[2], (f16)fv[3] };
        *((f16x4*)dst + off) = hv;
    }
}

// ---------------- kernel 2: QKV GEMM (256x64 tile, gload_lds) + bias + RoPE ----------------
// Q stored [bh][s][64] (pre-scaled by 0.125*log2e).
// K tiled+swizzled: [bh][s/64][s%64][chunk ^ (s&7)]   (chunk = 8 f16)
// V transposed tiled+swizzled: [bh][s/64][d][schunk ^ (d&7)]
__global__ __launch_bounds__(256) void qkv_gemm(
    const f16* __restrict__ xb, const f16* __restrict__ wq,
    const f16* __restrict__ wk, const f16* __restrict__ wv,
    const float* __restrict__ qb, const float* __restrict__ kb,
    const float* __restrict__ vb,
    const float* __restrict__ cosT, const float* __restrict__ sinT,
    f16* __restrict__ Q, f16* __restrict__ K, f16* __restrict__ Vt)
{
    extern __shared__ char smem[];
    f16* As = (f16*)smem;                   // [256][64] linear (content source-swizzled)
    f16* Bs = (f16*)(smem + 256*64*2);      // [64][64]
    f16* Cs = (f16*)smem;                   // [256][72] f16 epilogue (reuse)

    const int wg = xcd_swz(blockIdx.x, 84); // 672 blocks
    const int tynt = wg % 21, mt = wg / 21;
    const int ty = tynt / 7, nt = tynt % 7;
    const int m0 = mt * 256, n0 = nt * 64;

    const f16* w = (ty == 0) ? wq : (ty == 1) ? wk : wv;
    const float* bias = (ty == 0) ? qb : (ty == 1) ? kb : vb;

    const int tid = threadIdx.x;
    const int wv_ = tid >> 6, lane = tid & 63;
    const int g = lane >> 4, lr = lane & 15;
    const int lrow = lane >> 3;                       // 0..7 row within 8-row stage group
    const int cswz = (lane & 7) ^ (lrow & 7);         // source chunk XOR (lane-const)

    const int ch0 = ((0*4 + g) ^ (lr & 7)) * 8;
    const int ch1 = ((1*4 + g) ^ (lr & 7)) * 8;

    f32x4 acc[4][4] = {};

    for (int k0 = 0; k0 < HID; k0 += 64) {
        // stage A: 256x64, wave wv_ rows wv_*64 + p*8 .. +7
        #pragma unroll
        for (int p = 0; p < 8; p++) {
            int rt = wv_*64 + p*8;
            gload16(xb + (int64_t)(m0 + rt + lrow)*HID + k0 + cswz*8, As + rt*64);
        }
        // stage B: 64x64
        #pragma unroll
        for (int p = 0; p < 2; p++) {
            int rt = wv_*16 + p*8;
            gload16(w + (int64_t)(n0 + rt + lrow)*HID + k0 + cswz*8, Bs + rt*64);
        }
        __syncthreads();
        #pragma unroll
        for (int kc = 0; kc < 2; kc++) {
            const int ch = kc ? ch1 : ch0;
            f16x8 af[4], bf[4];
            #pragma unroll
            for (int fm = 0; fm < 4; fm++)
                af[fm] = *(const f16x8*)(As + (wv_*64 + fm*16 + lr)*64 + ch);
            #pragma unroll
            for (int fn = 0; fn < 4; fn++)
                bf[fn] = *(const f16x8*)(Bs + (fn*16 + lr)*64 + ch);
            #pragma unroll
            for (int fm = 0; fm < 4; fm++)
                #pragma unroll
                for (int fn = 0; fn < 4; fn++)
                    acc[fm][fn] = MFMA(af[fm], bf[fn], acc[fm][fn]);
        }
        __syncthreads();
    }

    // epilogue: acc -> Cs f16 (+bias)
    float bias_f[4];
    #pragma unroll
    for (int fn = 0; fn < 4; fn++) bias_f[fn] = bias[n0 + fn*16 + lr];
    #pragma unroll
    for (int fm = 0; fm < 4; fm++)
        #pragma unroll
        for (int fn = 0; fn < 4; fn++)
            #pragma unroll
            for (int j = 0; j < 4; j++)
                Cs[(wv_*64 + fm*16 + g*4 + j)*72 + fn*16 + lr] = (f16)(acc[fm][fn][j] + bias_f[fn]);
    __syncthreads();

    const int b = m0 / NS;
    const int s0 = m0 % NS;
    const int64_t bhbase = ((int64_t)(b*HN + nt)) * NS * HD;

    if (ty < 2) {
        // RoPE per row; thread r handles all 64 d
        const float scale = (ty == 0) ? 0.125f * LOG2E : 1.0f;
        const int r = tid, s = s0 + r;
        const f16* crow = Cs + r*72;
        const float* cr = cosT + s*64;
        const float* sr = sinT + s*64;
        f16 vals[64];
        #pragma unroll
        for (int i = 0; i < 4; i++) {
            f16x8 ylo = *(const f16x8*)(crow + i*8);
            f16x8 yhi = *(const f16x8*)(crow + 32 + i*8);
            #pragma unroll
            for (int h = 0; h < 2; h++) {
                f32x4 cl = *(const f32x4*)(cr + i*8 + h*4);
                f32x4 sl = *(const f32x4*)(sr + i*8 + h*4);
                f32x4 chh = *(const f32x4*)(cr + 32 + i*8 + h*4);
                f32x4 shh = *(const f32x4*)(sr + 32 + i*8 + h*4);
                #pragma unroll
                for (int j = 0; j < 4; j++) {
                    float lo = (float)ylo[h*4+j], hi = (float)yhi[h*4+j];
                    vals[i*8 + h*4 + j]      = (f16)((lo*cl[j] - hi*sl[j]) * scale);
                    vals[32 + i*8 + h*4 + j] = (f16)((hi*chh[j] + lo*shh[j]) * scale);
                }
            }
        }
        if (ty == 0) {
            f16* p = Q + bhbase + (int64_t)s * HD;
            #pragma unroll
            for (int i = 0; i < 8; i++)
                *(f16x8*)(p + i*8) = *(f16x8*)(vals + i*8);
        } else {
            int tt = (s0 >> 6) + (r >> 6);
            int rt = r & 63;
            f16* base = K + bhbase + tt*4096 + rt*64;
            #pragma unroll
            for (int i = 0; i < 8; i++)
                *(f16x8*)(base + (i ^ (rt & 7))*8) = *(f16x8*)(vals + i*8);
        }
    } else {
        // V transposed: thread handles one d, 64 s
        const int d = tid & 63, sblk = tid >> 6, si0 = sblk * 64;
        f16 vals[64];
        #pragma unroll
        for (int i = 0; i < 64; i++)
            vals[i] = Cs[(si0 + i)*72 + d];
        int tt = (s0 >> 6) + sblk;
        f16* base = Vt + bhbase + tt*4096 + d*64;
        #pragma unroll
        for (int i = 0; i < 8; i++)
            *(f16x8*)(base + (i ^ (d & 7))*8) = *(f16x8*)(vals + i*8);
    }
}

// ---------------- kernel 3: flash attention ----------------
__global__ __launch_bounds__(256) void attn_kernel(
    const f16* __restrict__ Q, const f16* __restrict__ K2,
    const f16* __restrict__ V2, f16* __restrict__ O)
{
    __shared__ __align__(16) f16 KVs[2][2][4096];
    __shared__ __align__(16) f16 Pl[4][16][72];

    const int wg = xcd_swz(blockIdx.x, 112);  // 896 blocks
    const int qb = wg % 32, bh = wg / 32;
    const int tid = threadIdx.x, w = tid >> 6, lane = tid & 63;
    const int g = lane >> 4, lr = lane & 15;
    const int q0 = qb * 64 + w * 16;

    const int64_t bhoff = (int64_t)bh * NS * HD;
    const f16* Qp = Q + bhoff;
    const f16* Kp = K2 + bhoff;
    const f16* Vp = V2 + bhoff;

    f16x8 aq0 = *(const f16x8*)(Qp + (q0 + lr) * HD + g * 8);
    f16x8 aq1 = *(const f16x8*)(Qp + (q0 + lr) * HD + 32 + g * 8);

    const int stoff = w * 1024 + lane * 8;
    const int ldoff = w * 1024;

    gload16(Kp + stoff,       &KVs[0][0][ldoff]);
    gload16(Kp + stoff + 512, &KVs[0][0][ldoff + 512]);
    gload16(Vp + stoff,       &KVs[0][1][ldoff]);
    gload16(Vp + stoff + 512, &KVs[0][1][ldoff + 512]);
    __syncthreads();

    f32x4 accO[4] = {};
    float mrun = -1e30f, srun = 0.f;

    const int ch0 = (g ^ (lr & 7)) * 8;
    const int ch1 = ((4 + g) ^ (lr & 7)) * 8;

    int buf = 0;
    for (int t = 0; t < NS / 64; ++t) {
        if (t + 1 < NS / 64) {
            const f16* ks = Kp + (t + 1) * 4096 + stoff;
            const f16* vs = Vp + (t + 1) * 4096 + stoff;
            gload16(ks,       &KVs[buf ^ 1][0][ldoff]);
            gload16(ks + 512, &KVs[buf ^ 1][0][ldoff + 512]);
            gload16(vs,       &KVs[buf ^ 1][1][ldoff]);
            gload16(vs + 512, &KVs[buf ^ 1][1][ldoff + 512]);
        }
        const f16* Ks = &KVs[buf][0][0];
        const f16* Vs = &KVs[buf][1][0];

        f32x4 sf[4];
        __builtin_amdgcn_s_setprio(1);
        #pragma unroll
        for (int kt = 0; kt < 4; ++kt) {
            const f16* kl = Ks + (kt * 16 + lr) * 64;
            f16x8 k0 = *(const f16x8*)(kl + ch0);
            f16x8 k1 = *(const f16x8*)(kl + ch1);
            f32x4 z = {};
            z = MFMA(k0, aq0, z);
            z = MFMA(k1, aq1, z);
            sf[kt] = z;
        }
        __builtin_amdgcn_s_setprio(0);

        // row max (max3-friendly trees) + 2 shfls
        float m0a = fmaxf(fmaxf(sf[0][0], sf[0][1]), fmaxf(sf[0][2], sf[0][3]));
        float m1a = fmaxf(fmaxf(sf[1][0], sf[1][1]), fmaxf(sf[1][2], sf[1][3]));
        float m2a = fmaxf(fmaxf(sf[2][0], sf[2][1]), fmaxf(sf[2][2], sf[2][3]));
        float m3a = fmaxf(fmaxf(sf[3][0], sf[3][1]), fmaxf(sf[3][2], sf[3][3]));
        float pmax = fmaxf(fmaxf(m0a, m1a), fmaxf(m2a, m3a));
        pmax = fmaxf(pmax, __shfl_xor(pmax, 16, 64));
        pmax = fmaxf(pmax, __shfl_xor(pmax, 32, 64));

        // defer-max (T13): only rescale when the running max grew by > 8 (log2 units)
        if (!__all(pmax - mrun <= 8.0f)) {
            float mn = fmaxf(mrun, pmax);
            float corr = exp2f(mrun - mn);
            mrun = mn;
            srun *= corr;
            #pragma unroll
            for (int fn = 0; fn < 4; ++fn)
                #pragma unroll
                for (int j = 0; j < 4; ++j)
                    accO[fn][j] *= corr;
        }

        float pf[16];
        #pragma unroll
        for (int kt = 0; kt < 4; ++kt)
            #pragma unroll
            for (int j = 0; j < 4; ++j)
                pf[kt*4 + j] = exp2f(sf[kt][j] - mrun);

        float s0a = (pf[0] + pf[1]) + (pf[2] + pf[3]);
        float s1a = (pf[4] + pf[5]) + (pf[6] + pf[7]);
        float s2a = (pf[8] + pf[9]) + (pf[10] + pf[11]);
        float s3a = (pf[12] + pf[13]) + (pf[14] + pf[15]);
        float tsum = (s0a + s1a) + (s2a + s3a);
        tsum += __shfl_xor(tsum, 16, 64);
        tsum += __shfl_xor(tsum, 32, 64);
        srun += tsum;

        #pragma unroll
        for (int kt = 0; kt < 4; ++kt) {
            f16x4 pk = { (f16)pf[kt*4+0], (f16)pf[kt*4+1], (f16)pf[kt*4+2], (f16)pf[kt*4+3] };
            *(f16x4*)&Pl[w][lr][kt*16 + g*4] = pk;
        }
        f16x8 p0 = *(const f16x8*)&Pl[w][lr][g * 8];
        f16x8 p1 = *(const f16x8*)&Pl[w][lr][32 + g * 8];

        __builtin_amdgcn_s_setprio(1);
        #pragma unroll
        for (int fn = 0; fn < 4; ++fn) {
            const f16* vl = Vs + (fn * 16 + lr) * 64;
            f16x8 v0 = *(const f16x8*)(vl + ch0);
            f16x8 v1 = *(const f16x8*)(vl + ch1);
            accO[fn] = MFMA(v0, p0, accO[fn]);
            accO[fn] = MFMA(v1, p1, accO[fn]);
        }
        __builtin_amdgcn_s_setprio(0);
        __syncthreads();
        buf ^= 1;
    }

    const int b = bh / HN, h = bh % HN;
    const float inv = 1.0f / srun;
    const int q = q0 + lr;
    f16* orow = O + ((int64_t)b * NS + q) * PR + h * HD;
    #pragma unroll
    for (int fn = 0; fn < 4; ++fn) {
        f16x4 hv = { (f16)(accO[fn][0] * inv), (f16)(accO[fn][1] * inv),
                     (f16)(accO[fn][2] * inv), (f16)(accO[fn][3] * inv) };
        *(f16x4*)(orow + fn * 16 + g * 4) = hv;
    }
}

// ---------------- kernel 4: output projection (128x128, gload_lds) ----------------
__global__ __launch_bounds__(256) void oproj_gemm(
    const f16* __restrict__ Ob, const f16* __restrict__ wo,
    const float* __restrict__ ob, float* __restrict__ out)
{
    extern __shared__ char smem[];
    f16* As = (f16*)smem;                 // [128][64]
    f16* Bs = (f16*)(smem + 128*64*2);    // [128][64]

    const int wg = xcd_swz(blockIdx.x, 56);  // 448 blocks
    const int nt = wg % 7, mt = wg / 7;
    const int m0 = mt*128, n0 = nt*128;
    const int tid = threadIdx.x;
    const int wv_ = tid >> 6, lane = tid & 63;
    const int wm = wv_ >> 1, wn = wv_ & 1;
    const int g = lane >> 4, lr = lane & 15;
    const int lrow = lane >> 3;
    const int cswz = (lane & 7) ^ (lrow & 7);

    const int ch0 = (g ^ (lr & 7)) * 8;
    const int ch1 = ((4 + g) ^ (lr & 7)) * 8;

    f32x4 acc[4][4] = {};

    for (int k0 = 0; k0 < PR; k0 += 64) {
        #pragma unroll
        for (int p = 0; p < 4; p++) {
            int rt = wv_*32 + p*8;
            gload16(Ob + (int64_t)(m0 + rt + lrow)*PR + k0 + cswz*8, As + rt*64);
        }
        #pragma unroll
        for (int p = 0; p < 4; p++) {
            int rt = wv_*32 + p*8;
            gload16(wo + (int64_t)(n0 + rt + lrow)*PR + k0 + cswz*8, Bs + rt*64);
        }
        __syncthreads();
        #pragma unroll
        for (int kc = 0; kc < 2; kc++) {
            const int ch = kc ? ch1 : ch0;
            f16x8 af[4], bf[4];
            #pragma unroll
            for (int fm = 0; fm < 4; fm++)
                af[fm] = *(const f16x8*)(As + (wm*64 + fm*16 + lr)*64 + ch);
            #pragma unroll
            for (int fn = 0; fn < 4; fn++)
                bf[fn] = *(const f16x8*)(Bs + (wn*64 + fn*16 + lr)*64 + ch);
            #pragma unroll
            for (int fm = 0; fm < 4; fm++)
                #pragma unroll
                for (int fn = 0; fn < 4; fn++)
                    acc[fm][fn] = MFMA(af[fm], bf[fn], acc[fm][fn]);
        }
        __syncthreads();
    }

    float bias_f[4];
    #pragma unroll
    for (int fn = 0; fn < 4; fn++) bias_f[fn] = ob[n0 + wn*64 + fn*16 + lr];
    #pragma unroll
    for (int fm = 0; fm < 4; fm++)
        #pragma unroll
        for (int fn = 0; fn < 4; fn++)
            #pragma unroll
            for (int j = 0; j < 4; j++) {
                int row = m0 + wm*64 + fm*16 + g*4 + j;
                int col = n0 + wn*64 + fn*16 + lr;
                out[(int64_t)row*HID + col] = acc[fm][fn][j] + bias_f[fn];
            }
}

extern "C" void kernel_launch(void* const* d_in, const int* in_sizes, int n_in,
                              void* d_out, int out_size, void* d_ws, size_t ws_size,
                              hipStream_t stream) {
    const float* x    = (const float*)d_in[0];
    const float* cosT = (const float*)d_in[1];
    const float* sinT = (const float*)d_in[2];
    const float* qw   = (const float*)d_in[3];
    const float* qb   = (const float*)d_in[4];
    const float* kw   = (const float*)d_in[5];
    const float* kb   = (const float*)d_in[6];
    const float* vw   = (const float*)d_in[7];
    const float* vb   = (const float*)d_in[8];
    const float* ow   = (const float*)d_in[9];
    const float* ob   = (const float*)d_in[10];
    float* out = (float*)d_out;

    char* ws = (char*)d_ws;
    f16* xb = (f16*)ws;  ws += (size_t)NM * HID * 2;
    f16* wqf = (f16*)ws; ws += (size_t)PR * HID * 2;
    f16* wkf = (f16*)ws; ws += (size_t)PR * HID * 2;
    f16* wvf = (f16*)ws; ws += (size_t)PR * HID * 2;
    f16* wof = (f16*)ws; ws += (size_t)HID * PR * 2;
    f16* Qb = (f16*)ws;  ws += (size_t)NB * HN * NS * HD * 2;
    f16* Kb = (f16*)ws;  ws += (size_t)NB * HN * NS * HD * 2;
    f16* Vt = (f16*)ws;  ws += (size_t)NB * HN * HD * NS * 2;
    f16* Obuf = (f16*)ws; ws += (size_t)NM * PR * 2;

    conv_kernel<<<dim3(2048), dim3(256), 0, stream>>>(x, qw, kw, vw, ow, xb, wqf, wkf, wvf, wof);
    qkv_gemm<<<dim3(672), dim3(256), 40960, stream>>>(xb, wqf, wkf, wvf, qb, kb, vb, cosT, sinT, Qb, Kb, Vt);
    attn_kernel<<<dim3(896), dim3(256), 0, stream>>>(Qb, Kb, Vt, Obuf);
    oproj_gemm<<<dim3(448), dim3(256), 32768, stream>>>(Obuf, wof, ob, out);
}

// Round 5
// 222.579 us; speedup vs baseline: 1.7324x; 1.1432x over previous
//
#include <hip/hip_runtime.h>

typedef _Float16 f16;
typedef __attribute__((ext_vector_type(8))) _Float16 f16x8;
typedef __attribute__((ext_vector_type(4))) _Float16 f16x4;
typedef __attribute__((ext_vector_type(4))) float f32x4;

#define MFMA(a,b,c) __builtin_amdgcn_mfma_f32_16x16x32_f16(a,b,c,0,0,0)

constexpr int HN = 7, HD = 64, HID = 896, PR = 448;
constexpr int NB = 4, NS = 2048, NM = NB * NS;
constexpr float LOG2E = 1.44269504088896f;

__device__ __forceinline__ void gload16(const f16* g, f16* l) {
    __builtin_amdgcn_global_load_lds(
        (const __attribute__((address_space(1))) void*)g,
        (__attribute__((address_space(3))) void*)l,
        16, 0, 0);
}

__device__ __forceinline__ int xcd_swz(int orig, int per) {
    return (orig & 7) * per + (orig >> 3);
}

// ---------------- kernel 1: fp32 -> f16 conversion ----------------
__global__ __launch_bounds__(256) void conv_kernel(
    const float* __restrict__ x,  const float* __restrict__ qw,
    const float* __restrict__ kw, const float* __restrict__ vw,
    const float* __restrict__ ow,
    f16* __restrict__ xb, f16* __restrict__ wq, f16* __restrict__ wk,
    f16* __restrict__ wv, f16* __restrict__ wo)
{
    const int XV = NM * HID / 4;
    const int WV = PR * HID / 4;
    const int TOT = XV + 4 * WV;
    int64_t stride = (int64_t)gridDim.x * blockDim.x;
    for (int64_t v = (int64_t)blockIdx.x * 256 + threadIdx.x; v < TOT; v += stride) {
        const float* src; f16* dst; int64_t off;
        if (v < XV)               { src = x;  dst = xb; off = v; }
        else if (v < XV + WV)     { src = qw; dst = wq; off = v - XV; }
        else if (v < XV + 2*WV)   { src = kw; dst = wk; off = v - XV - WV; }
        else if (v < XV + 3*WV)   { src = vw; dst = wv; off = v - XV - 2*WV; }
        else                      { src = ow; dst = wo; off = v - XV - 3*WV; }
        f32x4 fv = *((const f32x4*)src + off);
        f16x4 hv = { (f16)fv[0], (f16)fv[1], (f16)fv[2], (f16)fv[3] };
        *((f16x4*)dst + off) = hv;
    }
}

// ---------------- kernel 2: QKV GEMM (128x64, gload_lds) + bias + RoPE ----------------
// Q stored [bh][s][64] (pre-scaled by 0.125*log2e).
// K tiled+swizzled: [bh][s/64][s%64][chunk ^ (s&7)]
// V transposed tiled+swizzled: [bh][s/64][d][schunk ^ (d&7)]
__global__ __launch_bounds__(256) void qkv_gemm(
    const f16* __restrict__ xb, const f16* __restrict__ wq,
    const f16* __restrict__ wk, const f16* __restrict__ wv,
    const float* __restrict__ qb, const float* __restrict__ kb,
    const float* __restrict__ vb,
    const float* __restrict__ cosT, const float* __restrict__ sinT,
    f16* __restrict__ Q, f16* __restrict__ K, f16* __restrict__ Vt)
{
    extern __shared__ char smem[];
    f16* As = (f16*)smem;                   // [128][64] linear (source-swizzled)
    f16* Bs = (f16*)(smem + 128*64*2);      // [64][64]
    f16* Cs = (f16*)smem;                   // [128][72] f16 epilogue (reuse)

    const int wg = xcd_swz(blockIdx.x, 168); // 1344 blocks
    const int tynt = wg % 21, mt = wg / 21;
    const int ty = tynt / 7, nt = tynt % 7;
    const int m0 = mt * 128, n0 = nt * 64;

    const f16* w = (ty == 0) ? wq : (ty == 1) ? wk : wv;
    const float* bias = (ty == 0) ? qb : (ty == 1) ? kb : vb;

    const int tid = threadIdx.x;
    const int wv_ = tid >> 6, lane = tid & 63;
    const int wm = wv_ >> 1, wn = wv_ & 1;
    const int g = lane >> 4, lr = lane & 15;
    const int lrow = lane >> 3;
    const int cswz = (lane & 7) ^ (lrow & 7);

    const int ch0 = (g ^ (lr & 7)) * 8;
    const int ch1 = ((4 + g) ^ (lr & 7)) * 8;

    f32x4 acc[4][2] = {};

    for (int k0 = 0; k0 < HID; k0 += 64) {
        #pragma unroll
        for (int p = 0; p < 4; p++) {
            int rt = wv_*32 + p*8;
            gload16(xb + (int64_t)(m0 + rt + lrow)*HID + k0 + cswz*8, As + rt*64);
        }
        #pragma unroll
        for (int p = 0; p < 2; p++) {
            int rt = wv_*16 + p*8;
            gload16(w + (int64_t)(n0 + rt + lrow)*HID + k0 + cswz*8, Bs + rt*64);
        }
        __syncthreads();
        #pragma unroll
        for (int kc = 0; kc < 2; kc++) {
            const int ch = kc ? ch1 : ch0;
            f16x8 af[4], bf[2];
            #pragma unroll
            for (int fm = 0; fm < 4; fm++)
                af[fm] = *(const f16x8*)(As + (wm*64 + fm*16 + lr)*64 + ch);
            #pragma unroll
            for (int fn = 0; fn < 2; fn++)
                bf[fn] = *(const f16x8*)(Bs + (wn*32 + fn*16 + lr)*64 + ch);
            #pragma unroll
            for (int fm = 0; fm < 4; fm++)
                #pragma unroll
                for (int fn = 0; fn < 2; fn++)
                    acc[fm][fn] = MFMA(af[fm], bf[fn], acc[fm][fn]);
        }
        __syncthreads();
    }

    float bias_f[2];
    #pragma unroll
    for (int fn = 0; fn < 2; fn++) bias_f[fn] = bias[n0 + wn*32 + fn*16 + lr];
    #pragma unroll
    for (int fm = 0; fm < 4; fm++)
        #pragma unroll
        for (int fn = 0; fn < 2; fn++)
            #pragma unroll
            for (int j = 0; j < 4; j++)
                Cs[(wm*64 + fm*16 + g*4 + j)*72 + wn*32 + fn*16 + lr] = (f16)(acc[fm][fn][j] + bias_f[fn]);
    __syncthreads();

    const int b = m0 / NS;
    const int s0 = m0 % NS;
    const int64_t bhbase = ((int64_t)(b*HN + nt)) * NS * HD;

    if (ty < 2) {
        // RoPE: 2 threads per row, 32 d each
        const float scale = (ty == 0) ? 0.125f * LOG2E : 1.0f;
        const int r = tid >> 1, d0 = (tid & 1) * 32, s = s0 + r;
        const f16* crow = Cs + r*72;
        f16 vals[32];
        if (d0 == 0) {
            #pragma unroll
            for (int i = 0; i < 8; i++) {
                f32x4 cl = *(const f32x4*)(cosT + s*64 + i*4);
                f32x4 sl = *(const f32x4*)(sinT + s*64 + i*4);
                #pragma unroll
                for (int j = 0; j < 4; j++) {
                    float lo = (float)crow[i*4+j], hi = (float)crow[32 + i*4+j];
                    vals[i*4 + j] = (f16)((lo*cl[j] - hi*sl[j]) * scale);
                }
            }
        } else {
            #pragma unroll
            for (int i = 0; i < 8; i++) {
                f32x4 cl = *(const f32x4*)(cosT + s*64 + 32 + i*4);
                f32x4 sl = *(const f32x4*)(sinT + s*64 + 32 + i*4);
                #pragma unroll
                for (int j = 0; j < 4; j++) {
                    float lo = (float)crow[i*4+j], hi = (float)crow[32 + i*4+j];
                    vals[i*4 + j] = (f16)((hi*cl[j] + lo*sl[j]) * scale);
                }
            }
        }
        if (ty == 0) {
            f16* p = Q + bhbase + (int64_t)s * HD + d0;
            #pragma unroll
            for (int i = 0; i < 4; i++)
                *(f16x8*)(p + i*8) = *(f16x8*)(vals + i*8);
        } else {
            int tt = (s0 >> 6) + (r >> 6);
            int rt = r & 63;
            f16* base = K + bhbase + tt*4096 + rt*64;
            #pragma unroll
            for (int i = 0; i < 4; i++)
                *(f16x8*)(base + (((d0>>3) + i) ^ (rt & 7))*8) = *(f16x8*)(vals + i*8);
        }
    } else {
        // V transpose: thread handles one d, 32 s
        const int d = tid & 63, sblk = tid >> 6, si0 = sblk * 32;
        f16 vals[32];
        #pragma unroll
        for (int i = 0; i < 32; i++)
            vals[i] = Cs[(si0 + i)*72 + d];
        int tt = (s0 >> 6) + (si0 >> 6);
        int sb = si0 & 63;
        f16* base = Vt + bhbase + tt*4096 + d*64;
        #pragma unroll
        for (int i = 0; i < 4; i++)
            *(f16x8*)(base + (((sb>>3) + i) ^ (d & 7))*8) = *(f16x8*)(vals + i*8);
    }
}

// ---------------- kernel 3: flash attention (32 q/wave, 128 q/block) ----------------
__global__ __launch_bounds__(256) void attn_kernel(
    const f16* __restrict__ Q, const f16* __restrict__ K2,
    const f16* __restrict__ V2, f16* __restrict__ O)
{
    __shared__ __align__(16) f16 KVs[2][2][4096];
    __shared__ __align__(16) f16 Pl[4][32][64];   // chunk-XOR swizzled, no pad

    const int wg = xcd_swz(blockIdx.x, 56);       // 448 blocks
    const int qb = wg & 15, bh = wg >> 4;
    const int tid = threadIdx.x, w = tid >> 6, lane = tid & 63;
    const int g = lane >> 4, lr = lane & 15;
    const int q0 = qb * 128 + w * 32;

    const int64_t bhoff = (int64_t)bh * NS * HD;
    const f16* Qp = Q + bhoff;
    const f16* Kp = K2 + bhoff;
    const f16* Vp = V2 + bhoff;

    f16x8 aq[2][2];
    #pragma unroll
    for (int qh = 0; qh < 2; qh++) {
        aq[qh][0] = *(const f16x8*)(Qp + (q0 + qh*16 + lr) * HD + g * 8);
        aq[qh][1] = *(const f16x8*)(Qp + (q0 + qh*16 + lr) * HD + 32 + g * 8);
    }

    const int stoff = w * 1024 + lane * 8;
    const int ldoff = w * 1024;

    gload16(Kp + stoff,       &KVs[0][0][ldoff]);
    gload16(Kp + stoff + 512, &KVs[0][0][ldoff + 512]);
    gload16(Vp + stoff,       &KVs[0][1][ldoff]);
    gload16(Vp + stoff + 512, &KVs[0][1][ldoff + 512]);
    __syncthreads();

    f32x4 accO[2][4] = {};
    float mrun[2] = {-1e30f, -1e30f}, srun[2] = {0.f, 0.f};

    const int ch0 = (g ^ (lr & 7)) * 8;         // chunk g of the 64-col row
    const int ch1 = ((4 + g) ^ (lr & 7)) * 8;   // chunk 4+g
    const int pswz = (lr & 7) * 8;              // write-side chunk XOR (bits 3..5)

    int buf = 0;
    for (int t = 0; t < NS / 64; ++t) {
        if (t + 1 < NS / 64) {
            const f16* ks = Kp + (t + 1) * 4096 + stoff;
            const f16* vs = Vp + (t + 1) * 4096 + stoff;
            gload16(ks,       &KVs[buf ^ 1][0][ldoff]);
            gload16(ks + 512, &KVs[buf ^ 1][0][ldoff + 512]);
            gload16(vs,       &KVs[buf ^ 1][1][ldoff]);
            gload16(vs + 512, &KVs[buf ^ 1][1][ldoff + 512]);
        }
        const f16* Ks = &KVs[buf][0][0];
        const f16* Vs = &KVs[buf][1][0];

        // QK^T swapped: D[k][q=lr] per q-half; K frags shared across halves
        f32x4 sf[2][4];
        __builtin_amdgcn_s_setprio(1);
        #pragma unroll
        for (int kt = 0; kt < 4; ++kt) {
            const f16* kl = Ks + (kt * 16 + lr) * 64;
            f16x8 k0 = *(const f16x8*)(kl + ch0);
            f16x8 k1 = *(const f16x8*)(kl + ch1);
            #pragma unroll
            for (int qh = 0; qh < 2; ++qh) {
                f32x4 z = {};
                z = MFMA(k0, aq[qh][0], z);
                z = MFMA(k1, aq[qh][1], z);
                sf[qh][kt] = z;
            }
        }
        __builtin_amdgcn_s_setprio(0);

        float pmax[2];
        #pragma unroll
        for (int qh = 0; qh < 2; ++qh) {
            float m0a = fmaxf(fmaxf(sf[qh][0][0], sf[qh][0][1]), fmaxf(sf[qh][0][2], sf[qh][0][3]));
            float m1a = fmaxf(fmaxf(sf[qh][1][0], sf[qh][1][1]), fmaxf(sf[qh][1][2], sf[qh][1][3]));
            float m2a = fmaxf(fmaxf(sf[qh][2][0], sf[qh][2][1]), fmaxf(sf[qh][2][2], sf[qh][2][3]));
            float m3a = fmaxf(fmaxf(sf[qh][3][0], sf[qh][3][1]), fmaxf(sf[qh][3][2], sf[qh][3][3]));
            float pm = fmaxf(fmaxf(m0a, m1a), fmaxf(m2a, m3a));
            pm = fmaxf(pm, __shfl_xor(pm, 16, 64));
            pm = fmaxf(pm, __shfl_xor(pm, 32, 64));
            pmax[qh] = pm;
        }

        if (!__all(pmax[0] - mrun[0] <= 8.0f && pmax[1] - mrun[1] <= 8.0f)) {
            #pragma unroll
            for (int qh = 0; qh < 2; ++qh) {
                float mn = fmaxf(mrun[qh], pmax[qh]);
                float corr = exp2f(mrun[qh] - mn);
                mrun[qh] = mn;
                srun[qh] *= corr;
                #pragma unroll
                for (int fn = 0; fn < 4; ++fn)
                    #pragma unroll
                    for (int j = 0; j < 4; ++j)
                        accO[qh][fn][j] *= corr;
            }
        }

        #pragma unroll
        for (int qh = 0; qh < 2; ++qh) {
            #pragma unroll
            for (int kt = 0; kt < 4; ++kt)
                #pragma unroll
                for (int j = 0; j < 4; ++j)
                    sf[qh][kt][j] = exp2f(sf[qh][kt][j] - mrun[qh]);
            float s0a = (sf[qh][0][0] + sf[qh][0][1]) + (sf[qh][0][2] + sf[qh][0][3]);
            float s1a = (sf[qh][1][0] + sf[qh][1][1]) + (sf[qh][1][2] + sf[qh][1][3]);
            float s2a = (sf[qh][2][0] + sf[qh][2][1]) + (sf[qh][2][2] + sf[qh][2][3]);
            float s3a = (sf[qh][3][0] + sf[qh][3][1]) + (sf[qh][3][2] + sf[qh][3][3]);
            float tsum = (s0a + s1a) + (s2a + s3a);
            tsum += __shfl_xor(tsum, 16, 64);
            tsum += __shfl_xor(tsum, 32, 64);
            srun[qh] += tsum;
            #pragma unroll
            for (int kt = 0; kt < 4; ++kt) {
                f16x4 pk = { (f16)sf[qh][kt][0], (f16)sf[qh][kt][1],
                             (f16)sf[qh][kt][2], (f16)sf[qh][kt][3] };
                // column k stored at chunk (k>>3)^(lr&7), keep low 3 bits
                *(f16x4*)&Pl[w][qh*16 + lr][(kt*16 + g*4) ^ pswz] = pk;
            }
        }

        f16x8 p0[2], p1[2];
        #pragma unroll
        for (int qh = 0; qh < 2; ++qh) {
            p0[qh] = *(const f16x8*)&Pl[w][qh*16 + lr][ch0];   // chunk g
            p1[qh] = *(const f16x8*)&Pl[w][qh*16 + lr][ch1];   // chunk 4+g  (was the OOB bug)
        }

        __builtin_amdgcn_s_setprio(1);
        #pragma unroll
        for (int fn = 0; fn < 4; ++fn) {
            const f16* vl = Vs + (fn * 16 + lr) * 64;
            f16x8 v0 = *(const f16x8*)(vl + ch0);
            f16x8 v1 = *(const f16x8*)(vl + ch1);
            #pragma unroll
            for (int qh = 0; qh < 2; ++qh) {
                accO[qh][fn] = MFMA(v0, p0[qh], accO[qh][fn]);
                accO[qh][fn] = MFMA(v1, p1[qh], accO[qh][fn]);
            }
        }
        __builtin_amdgcn_s_setprio(0);
        __syncthreads();
        buf ^= 1;
    }

    const int b = bh / HN, h = bh % HN;
    #pragma unroll
    for (int qh = 0; qh < 2; ++qh) {
        const float inv = 1.0f / srun[qh];
        const int q = q0 + qh*16 + lr;
        f16* orow = O + ((int64_t)b * NS + q) * PR + h * HD;
        #pragma unroll
        for (int fn = 0; fn < 4; ++fn) {
            f16x4 hv = { (f16)(accO[qh][fn][0] * inv), (f16)(accO[qh][fn][1] * inv),
                         (f16)(accO[qh][fn][2] * inv), (f16)(accO[qh][fn][3] * inv) };
            *(f16x4*)(orow + fn * 16 + g * 4) = hv;
        }
    }
}

// ---------------- kernel 4: output projection (128x64, gload_lds) ----------------
__global__ __launch_bounds__(256) void oproj_gemm(
    const f16* __restrict__ Ob, const f16* __restrict__ wo,
    const float* __restrict__ ob, float* __restrict__ out)
{
    extern __shared__ char smem[];
    f16* As = (f16*)smem;                 // [128][64]
    f16* Bs = (f16*)(smem + 128*64*2);    // [64][64]

    const int wg = xcd_swz(blockIdx.x, 112);  // 896 blocks
    const int nt = wg % 14, mt = wg / 14;
    const int m0 = mt*128, n0 = nt*64;
    const int tid = threadIdx.x;
    const int wv_ = tid >> 6, lane = tid & 63;
    const int wm = wv_ >> 1, wn = wv_ & 1;
    const int g = lane >> 4, lr = lane & 15;
    const int lrow = lane >> 3;
    const int cswz = (lane & 7) ^ (lrow & 7);

    const int ch0 = (g ^ (lr & 7)) * 8;
    const int ch1 = ((4 + g) ^ (lr & 7)) * 8;

    f32x4 acc[4][2] = {};

    for (int k0 = 0; k0 < PR; k0 += 64) {
        #pragma unroll
        for (int p = 0; p < 4; p++) {
            int rt = wv_*32 + p*8;
            gload16(Ob + (int64_t)(m0 + rt + lrow)*PR + k0 + cswz*8, As + rt*64);
        }
        #pragma unroll
        for (int p = 0; p < 2; p++) {
            int rt = wv_*16 + p*8;
            gload16(wo + (int64_t)(n0 + rt + lrow)*PR + k0 + cswz*8, Bs + rt*64);
        }
        __syncthreads();
        #pragma unroll
        for (int kc = 0; kc < 2; kc++) {
            const int ch = kc ? ch1 : ch0;
            f16x8 af[4], bf[2];
            #pragma unroll
            for (int fm = 0; fm < 4; fm++)
                af[fm] = *(const f16x8*)(As + (wm*64 + fm*16 + lr)*64 + ch);
            #pragma unroll
            for (int fn = 0; fn < 2; fn++)
                bf[fn] = *(const f16x8*)(Bs + (wn*32 + fn*16 + lr)*64 + ch);
            #pragma unroll
            for (int fm = 0; fm < 4; fm++)
                #pragma unroll
                for (int fn = 0; fn < 2; fn++)
                    acc[fm][fn] = MFMA(af[fm], bf[fn], acc[fm][fn]);
        }
        __syncthreads();
    }

    float bias_f[2];
    #pragma unroll
    for (int fn = 0; fn < 2; fn++) bias_f[fn] = ob[n0 + wn*32 + fn*16 + lr];
    #pragma unroll
    for (int fm = 0; fm < 4; fm++)
        #pragma unroll
        for (int fn = 0; fn < 2; fn++)
            #pragma unroll
            for (int j = 0; j < 4; j++) {
                int row = m0 + wm*64 + fm*16 + g*4 + j;
                int col = n0 + wn*32 + fn*16 + lr;
                out[(int64_t)row*HID + col] = acc[fm][fn][j] + bias_f[fn];
            }
}

extern "C" void kernel_launch(void* const* d_in, const int* in_sizes, int n_in,
                              void* d_out, int out_size, void* d_ws, size_t ws_size,
                              hipStream_t stream) {
    const float* x    = (const float*)d_in[0];
    const float* cosT = (const float*)d_in[1];
    const float* sinT = (const float*)d_in[2];
    const float* qw   = (const float*)d_in[3];
    const float* qb   = (const float*)d_in[4];
    const float* kw   = (const float*)d_in[5];
    const float* kb   = (const float*)d_in[6];
    const float* vw   = (const float*)d_in[7];
    const float* vb   = (const float*)d_in[8];
    const float* ow   = (const float*)d_in[9];
    const float* ob   = (const float*)d_in[10];
    float* out = (float*)d_out;

    char* ws = (char*)d_ws;
    f16* xb = (f16*)ws;  ws += (size_t)NM * HID * 2;
    f16* wqf = (f16*)ws; ws += (size_t)PR * HID * 2;
    f16* wkf = (f16*)ws; ws += (size_t)PR * HID * 2;
    f16* wvf = (f16*)ws; ws += (size_t)PR * HID * 2;
    f16* wof = (f16*)ws; ws += (size_t)HID * PR * 2;
    f16* Qb = (f16*)ws;  ws += (size_t)NB * HN * NS * HD * 2;
    f16* Kb = (f16*)ws;  ws += (size_t)NB * HN * NS * HD * 2;
    f16* Vt = (f16*)ws;  ws += (size_t)NB * HN * HD * NS * 2;
    f16* Obuf = (f16*)ws; ws += (size_t)NM * PR * 2;

    conv_kernel<<<dim3(2048), dim3(256), 0, stream>>>(x, qw, kw, vw, ow, xb, wqf, wkf, wvf, wof);
    qkv_gemm<<<dim3(1344), dim3(256), 24576, stream>>>(xb, wqf, wkf, wvf, qb, kb, vb, cosT, sinT, Qb, Kb, Vt);
    attn_kernel<<<dim3(448), dim3(256), 0, stream>>>(Qb, Kb, Vt, Obuf);
    oproj_gemm<<<dim3(896), dim3(256), 24576, stream>>>(Obuf, wof, ob, out);
}